// Round 2
// baseline (33594.482 us; speedup 1.0000x reference)
//
#include <hip/hip_runtime.h>
#include <stdint.h>

// Problem constants
#define SLEN 512
#define NBATCH 64
#define EMB 1024
#define HID 1024
#define G4 4096            // 4*H
#define D2H 2048           // 2*H
#define CT 64              // chunk timesteps
#define NC (SLEN/CT)       // 8 chunks
#define CROWS (CT*NBATCH)  // 4096 rows per chunk per dir
#define HSLOT (NBATCH*D2H) // elems per h timestep slot

typedef __bf16 bf16x8 __attribute__((ext_vector_type(8)));
typedef float  f32x4  __attribute__((ext_vector_type(4)));

__device__ __forceinline__ ushort f2bf(float x){
  union { float f; uint32_t u; } v; v.f = x;
  uint32_t r = (v.u + 0x7fffu + ((v.u >> 16) & 1u)) >> 16;   // RNE
  return (ushort)r;
}
__device__ __forceinline__ float bf2f(ushort u){
  union { uint32_t u; float f; } v; v.u = ((uint32_t)u) << 16;
  return v.f;
}
__device__ __forceinline__ float sigm(float x){ return 1.f / (1.f + __expf(-x)); }
__device__ __forceinline__ float tanh_s(float x){ return 2.f / (1.f + __expf(-2.f*x)) - 1.f; }

__device__ __forceinline__ void async_ld16(const ushort* g, ushort* l){
  __builtin_amdgcn_global_load_lds(
      (const __attribute__((address_space(1))) uint32_t*)g,
      (__attribute__((address_space(3))) uint32_t*)l, 16, 0, 0);
}

// ---------------- zero a u32 region ----------------
__global__ void k_zero(uint32_t* p, int n){
  int i = blockIdx.x * 256 + threadIdx.x;
  if (i < n) p[i] = 0;
}

// ---------------- fp32 -> bf16 convert (vectorized x4) ----------------
__global__ void k_convert(const float4* __restrict__ src, ushort4* __restrict__ dst, int n4){
  int i = blockIdx.x * blockDim.x + threadIdx.x;
  if (i < n4){
    float4 v = src[i];
    ushort4 o; o.x = f2bf(v.x); o.y = f2bf(v.y); o.z = f2bf(v.z); o.w = f2bf(v.w);
    dst[i] = o;
  }
}

// ---------------- embedding gather for one chunk -> x_bf16 [CT][B][E] ----------
__global__ void k_gather_c(const int* __restrict__ inp, const float* __restrict__ emb,
                           ushort* __restrict__ xbf, int tbase){
  int row = blockIdx.x;            // i*64 + b  (i = local step)
  int s = tbase + (row >> 6), b = row & 63;
  int t = threadIdx.x;             // 256 threads, 4 floats each
  int v = inp[b * SLEN + s];
  float4 x = ((const float4*)(emb + (size_t)v * EMB))[t];
  ushort4 o; o.x = f2bf(x.x); o.y = f2bf(x.y); o.z = f2bf(x.z); o.w = f2bf(x.w);
  ((ushort4*)(xbf + (size_t)row * EMB))[t] = o;
}

// ---------------- chunk GEMM: C[d][4096rows][4096] = A[rows][K] @ W[d][4096][K]^T + bias[d]
// m97-style: 128x128 tile, BK=32, global_load_lds width 16, 16x16x32 bf16 MFMA
__global__ __launch_bounds__(256) void k_gemm(const ushort* __restrict__ A,
                                              const ushort* __restrict__ Bw,
                                              const float* __restrict__ bias,
                                              ushort* __restrict__ C, int K,
                                              size_t cDirStride){
  __shared__ __align__(16) ushort sA[128 * 32];
  __shared__ __align__(16) ushort sB[128 * 32];
  const int tid = threadIdx.x;
  const int d = blockIdx.z;
  const size_t mBase = (size_t)blockIdx.x * 128;
  const int nBase = blockIdx.y * 128;
  const ushort* Bd = Bw + (size_t)d * G4 * K;
  const float* biasd = bias + (size_t)d * G4;
  ushort* Cd = C + (size_t)d * cDirStride;
  const int w = tid >> 6, lane = tid & 63;
  const int quad = lane >> 4, c16 = lane & 15;
  const int m0 = (w >> 1) * 64, n0 = (w & 1) * 64;
  const int u0 = tid, u1 = tid + 256;
  const int r0 = u0 >> 2, k0 = (u0 & 3) * 8;
  const int r1 = u1 >> 2, k1 = (u1 & 3) * 8;

  f32x4 acc[4][4] = {};
  for (int kc = 0; kc < K; kc += 32){
    __syncthreads();   // protect LDS from previous iter's readers
    async_ld16(A  + (mBase + r0) * (size_t)K + kc + k0, sA + u0 * 8);
    async_ld16(A  + (mBase + r1) * (size_t)K + kc + k1, sA + u1 * 8);
    async_ld16(Bd + (size_t)(nBase + r0) * K + kc + k0, sB + u0 * 8);
    async_ld16(Bd + (size_t)(nBase + r1) * K + kc + k1, sB + u1 * 8);
    __syncthreads();   // drains vmcnt before use
    bf16x8 af[4], bfv[4];
#pragma unroll
    for (int mt = 0; mt < 4; ++mt)
      af[mt] = *(const bf16x8*)(sA + (m0 + mt * 16 + c16) * 32 + quad * 8);
#pragma unroll
    for (int nt = 0; nt < 4; ++nt)
      bfv[nt] = *(const bf16x8*)(sB + (n0 + nt * 16 + c16) * 32 + quad * 8);
#pragma unroll
    for (int mt = 0; mt < 4; ++mt)
#pragma unroll
      for (int nt = 0; nt < 4; ++nt)
        acc[mt][nt] = __builtin_amdgcn_mfma_f32_16x16x32_bf16(af[mt], bfv[nt], acc[mt][nt], 0, 0, 0);
  }
  // epilogue: +bias, store bf16.  D layout: col=lane&15, row=quad*4+r
#pragma unroll
  for (int nt = 0; nt < 4; ++nt){
    int col = nBase + n0 + nt * 16 + c16;
    float bv = biasd[col];
#pragma unroll
    for (int mt = 0; mt < 4; ++mt){
      size_t rowb = mBase + m0 + mt * 16 + quad * 4;
#pragma unroll
      for (int r = 0; r < 4; ++r)
        Cd[(rowb + r) * G4 + col] = f2bf(acc[mt][nt][r] + bv);
    }
  }
}

// ---------------- grid barrier (domain of 64 blocks) ----------------
__device__ __forceinline__ void grid_barrier(unsigned* cnt, unsigned* gen, unsigned nblk){
  __syncthreads();
  if (threadIdx.x == 0){
    unsigned g = __hip_atomic_load(gen, __ATOMIC_RELAXED, __HIP_MEMORY_SCOPE_AGENT);
    if (__hip_atomic_fetch_add(cnt, 1u, __ATOMIC_ACQ_REL, __HIP_MEMORY_SCOPE_AGENT) == nblk - 1){
      __hip_atomic_store(cnt, 0u, __ATOMIC_RELAXED, __HIP_MEMORY_SCOPE_AGENT);
      __hip_atomic_fetch_add(gen, 1u, __ATOMIC_RELEASE, __HIP_MEMORY_SCOPE_AGENT);
    } else {
      while (__hip_atomic_load(gen, __ATOMIC_ACQUIRE, __HIP_MEMORY_SCOPE_AGENT) == g)
        __builtin_amdgcn_s_sleep(1);
    }
  }
  __syncthreads();
}

// ---------------- persistent recurrent kernel for ONE chunk of CT steps ----------
// 128 blocks: (dir, 16 hidden units).  Per wave: 16 batch rows x 4 gate tiles 16x16x32.
// mode 0 (layer0): hseq = CT slots, slot i = h(tbase+i); h_init = h(tbase-1)
// mode 1 (layer1): hseq = 2 slots, invariant: current h in slot 0 at chunk boundary
__global__ __launch_bounds__(256) void k_rec(const ushort* __restrict__ xw,
                                             const ushort* __restrict__ whh,
                                             const ushort* __restrict__ h_init,
                                             ushort* __restrict__ hseq,
                                             float* __restrict__ cst,
                                             unsigned* __restrict__ bar, int mode, int tbase,
                                             const int* __restrict__ tgt_idx,
                                             float* __restrict__ tgt_out){
  const int tid = threadIdx.x;
  const int bx = blockIdx.x;
  const int d  = bx >> 6;            // direction
  const int j0 = (bx & 63) << 4;     // 16 hidden units
  const int w = tid >> 6, lane = tid & 63;
  const int quad = lane >> 4, c16 = lane & 15;
  const int m0 = w << 4;             // wave's 16 batch rows
  unsigned* cnt = bar + 0;
  unsigned* gen = bar + 8;
  // NOTE: each direction gets its own bar domain via pointer offset at launch? No —
  // both dirs share this kernel; split domains by d:
  cnt = bar + d * 16;
  gen = bar + d * 16 + 8;

  const ushort* wr[4];
#pragma unroll
  for (int g = 0; g < 4; ++g)
    wr[g] = whh + ((size_t)d * G4 + g * HID + j0 + c16) * HID;  // B-frag: n = lane&15
  const int acol = d * HID;
  const int arow = m0 + c16;         // A-frag: m = lane&15

  int tgtm[4];
#pragma unroll
  for (int r = 0; r < 4; ++r) tgtm[r] = mode ? tgt_idx[m0 + quad * 4 + r] : -1;

  // cell state: load from cst, keep in registers across the chunk, store back
  float cv[4];
#pragma unroll
  for (int r = 0; r < 4; ++r)
    cv[r] = cst[((size_t)(d * NBATCH + m0 + quad * 4 + r)) * HID + j0 + c16];

  for (int i = 0; i < CT; ++i){
    const ushort* hprev = mode ? hseq + (size_t)(i & 1) * HSLOT
                               : (i == 0 ? h_init : hseq + (size_t)(i - 1) * HSLOT);
    ushort* hout = mode ? hseq + (size_t)(1 - (i & 1)) * HSLOT
                        : hseq + (size_t)i * HSLOT;

    // xw gate pre-activations for this lane's 4 rows x 4 gates
    ushort xwv[4][4];
    const ushort* xwb = xw + ((size_t)d * CROWS + (size_t)i * NBATCH) * G4;
#pragma unroll
    for (int g = 0; g < 4; ++g)
#pragma unroll
      for (int r = 0; r < 4; ++r)
        xwv[g][r] = xwb[(size_t)(m0 + quad * 4 + r) * G4 + g * HID + j0 + c16];

    f32x4 acc[4] = {};
    const ushort* ap = hprev + (size_t)arow * D2H + acol;
#pragma unroll 4
    for (int kc = 0; kc < HID; kc += 32){
      bf16x8 a = *(const bf16x8*)(ap + kc + quad * 8);
#pragma unroll
      for (int g = 0; g < 4; ++g){
        bf16x8 b = *(const bf16x8*)(wr[g] + kc + quad * 8);
        acc[g] = __builtin_amdgcn_mfma_f32_16x16x32_bf16(a, b, acc[g], 0, 0, 0);
      }
    }

#pragma unroll
    for (int r = 0; r < 4; ++r){
      int m = m0 + quad * 4 + r;
      float gi = acc[0][r] + bf2f(xwv[0][r]);
      float gf = acc[1][r] + bf2f(xwv[1][r]);
      float gg = acc[2][r] + bf2f(xwv[2][r]);
      float go = acc[3][r] + bf2f(xwv[3][r]);
      float c = sigm(gf) * cv[r] + sigm(gi) * tanh_s(gg);
      float h = sigm(go) * tanh_s(c);
      cv[r] = c;
      hout[(size_t)m * D2H + acol + j0 + c16] = f2bf(h);
      if (tbase + i == tgtm[r]) tgt_out[(size_t)m * D2H + acol + j0 + c16] = h;
    }
    if (i != CT - 1) grid_barrier(cnt, gen, 64);
  }

#pragma unroll
  for (int r = 0; r < 4; ++r)
    cst[((size_t)(d * NBATCH + m0 + quad * 4 + r)) * HID + j0 + c16] = cv[r];
}

// ---------------- final: out[b] = sigmoid(dot(tgt[b], w_cls) + b_cls) ----------------
__global__ __launch_bounds__(256) void k_final(const float* __restrict__ tgt,
                                               const float* __restrict__ wc,
                                               const float* __restrict__ bc,
                                               float* __restrict__ out){
  int b = blockIdx.x, tid = threadIdx.x;
  const float4* tv = (const float4*)(tgt + (size_t)b * D2H);
  const float4* wv = (const float4*)wc;
  float s = 0.f;
  for (int i = tid; i < D2H / 4; i += 256){
    float4 a = tv[i], ww = wv[i];
    s += a.x * ww.x + a.y * ww.y + a.z * ww.z + a.w * ww.w;
  }
  for (int off = 32; off; off >>= 1) s += __shfl_down(s, off, 64);
  __shared__ float red[4];
  if ((tid & 63) == 0) red[tid >> 6] = s;
  __syncthreads();
  if (tid == 0){
    float tot = red[0] + red[1] + red[2] + red[3] + bc[0];
    out[b] = 1.f / (1.f + __expf(-tot));
  }
}

extern "C" void kernel_launch(void* const* d_in, const int* in_sizes, int n_in,
                              void* d_out, int out_size, void* d_ws, size_t ws_size,
                              hipStream_t stream){
  (void)in_sizes; (void)n_in; (void)out_size; (void)ws_size;
  const int*   inp   = (const int*)  d_in[0];
  const int*   tgtix = (const int*)  d_in[1];
  const float* emb   = (const float*)d_in[2];
  const float* wih0  = (const float*)d_in[3];
  const float* whh0  = (const float*)d_in[4];
  const float* bl0   = (const float*)d_in[5];
  const float* wih1  = (const float*)d_in[6];
  const float* whh1  = (const float*)d_in[7];
  const float* bl1   = (const float*)d_in[8];
  const float* wcls  = (const float*)d_in[9];
  const float* bcls  = (const float*)d_in[10];
  float* out = (float*)d_out;

  // ---- workspace carve (~170 MB total) ----
  char* p = (char*)d_ws;
  ushort* wih0b = (ushort*)p; p += (size_t)2 * G4 * 1024 * 2;   // 16 MB
  ushort* whh0b = (ushort*)p; p += (size_t)2 * G4 * 1024 * 2;   // 16 MB
  ushort* wih1b = (ushort*)p; p += (size_t)2 * G4 * 2048 * 2;   // 32 MB
  ushort* whh1b = (ushort*)p; p += (size_t)2 * G4 * 1024 * 2;   // 16 MB
  ushort* xbf   = (ushort*)p; p += (size_t)CROWS * EMB * 2;     // 8 MB (chunk)
  ushort* xw    = (ushort*)p; p += (size_t)2 * CROWS * G4 * 2;  // 64 MB (chunk, reused L0/L1)
  ushort* h0seq = (ushort*)p; p += (size_t)CT * HSLOT * 2;      // 16 MB (chunk h window)
  // ---- zeroed region (contiguous) ----
  char* zbase = p;
  ushort* h0zero = (ushort*)p; p += (size_t)HSLOT * 2;          // 256 KB
  ushort* h1buf  = (ushort*)p; p += (size_t)2 * HSLOT * 2;      // 512 KB (2 slots)
  float*  c0st   = (float*)p;  p += (size_t)2 * NBATCH * HID * 4; // 512 KB
  float*  c1st   = (float*)p;  p += (size_t)2 * NBATCH * HID * 4; // 512 KB
  unsigned* bar  = (unsigned*)p; p += 1024;                     // 2 domains x 32 u32, x2 layers
  size_t zbytes = (size_t)(p - zbase);
  // ---- end zero region ----
  float* tgtb = (float*)p; p += (size_t)NBATCH * D2H * 4;       // 512 KB

  int zn = (int)(zbytes / 4);
  k_zero<<<dim3((zn + 255) / 256), 256, 0, stream>>>((uint32_t*)zbase, zn);
  k_convert<<<dim3(8192),  256, 0, stream>>>((const float4*)wih0, (ushort4*)wih0b, 2 * G4 * 1024 / 4);
  k_convert<<<dim3(8192),  256, 0, stream>>>((const float4*)whh0, (ushort4*)whh0b, 2 * G4 * 1024 / 4);
  k_convert<<<dim3(16384), 256, 0, stream>>>((const float4*)wih1, (ushort4*)wih1b, 2 * G4 * 2048 / 4);
  k_convert<<<dim3(8192),  256, 0, stream>>>((const float4*)whh1, (ushort4*)whh1b, 2 * G4 * 1024 / 4);

  const size_t cds = (size_t)CROWS * G4;
  for (int c = 0; c < NC; ++c){
    int tbase = c * CT;
    k_gather_c<<<dim3(CROWS), 256, 0, stream>>>(inp, emb, xbf, tbase);
    // layer 0 chunk: xw = x @ w_ih0^T + b0 ; CT-step recurrence into h0seq window
    k_gemm<<<dim3(CROWS / 128, G4 / 128, 2), 256, 0, stream>>>(xbf, wih0b, bl0, xw, EMB, cds);
    k_rec<<<dim3(128), 256, 0, stream>>>(xw, whh0b,
                                         c == 0 ? h0zero : h0seq + (size_t)(CT - 1) * HSLOT,
                                         h0seq, c0st, bar, 0, tbase, tgtix, tgtb);
    // layer 1 chunk: xw = h0 @ w_ih1^T + b1 ; recurrence with target capture
    k_gemm<<<dim3(CROWS / 128, G4 / 128, 2), 256, 0, stream>>>(h0seq, wih1b, bl1, xw, D2H, cds);
    k_rec<<<dim3(128), 256, 0, stream>>>(xw, whh1b, h0zero,
                                         h1buf, c1st, bar + 32, 1, tbase, tgtix, tgtb);
  }

  k_final<<<dim3(NBATCH), 256, 0, stream>>>(tgtb, wcls, bcls, out);
}

// Round 3
// 15045.665 us; speedup vs baseline: 2.2328x; 2.2328x over previous
//
#include <hip/hip_runtime.h>
#include <stdint.h>

// Problem constants
#define SLEN 512
#define NBATCH 64
#define EMB 1024
#define HID 1024
#define G4 4096            // 4*H
#define D2H 2048           // 2*H
#define CT 64              // chunk timesteps
#define NC (SLEN/CT)       // 8 chunks
#define CROWS (CT*NBATCH)  // 4096 rows per chunk per dir
#define HSLOT (NBATCH*D2H) // elems per h timestep slot

typedef __bf16 bf16x8 __attribute__((ext_vector_type(8)));
typedef float  f32x4  __attribute__((ext_vector_type(4)));

__device__ __forceinline__ ushort f2bf(float x){
  union { float f; uint32_t u; } v; v.f = x;
  uint32_t r = (v.u + 0x7fffu + ((v.u >> 16) & 1u)) >> 16;   // RNE
  return (ushort)r;
}
__device__ __forceinline__ float bf2f(uint32_t u){
  union { uint32_t u; float f; } v; v.u = u << 16;
  return v.f;
}
__device__ __forceinline__ float sigm(float x){ return 1.f / (1.f + __expf(-x)); }
__device__ __forceinline__ float tanh_s(float x){ return 2.f / (1.f + __expf(-2.f*x)) - 1.f; }

__device__ __forceinline__ void async_ld16(const ushort* g, ushort* l){
  __builtin_amdgcn_global_load_lds(
      (const __attribute__((address_space(1))) uint32_t*)g,
      (__attribute__((address_space(3))) uint32_t*)l, 16, 0, 0);
}

// ---------------- zero a u32 region ----------------
__global__ void k_zero(uint32_t* p, int n){
  int i = blockIdx.x * 256 + threadIdx.x;
  if (i < n) p[i] = 0;
}

// ---------------- fp32 -> bf16 convert (vectorized x4) ----------------
__global__ void k_convert(const float4* __restrict__ src, ushort4* __restrict__ dst, int n4){
  int i = blockIdx.x * blockDim.x + threadIdx.x;
  if (i < n4){
    float4 v = src[i];
    ushort4 o; o.x = f2bf(v.x); o.y = f2bf(v.y); o.z = f2bf(v.z); o.w = f2bf(v.w);
    dst[i] = o;
  }
}

// ---------------- embedding gather for one chunk -> x_bf16 [CT][B][E] ----------
__global__ void k_gather_c(const int* __restrict__ inp, const float* __restrict__ emb,
                           ushort* __restrict__ xbf, int tbase){
  int row = blockIdx.x;            // i*64 + b
  int s = tbase + (row >> 6), b = row & 63;
  int t = threadIdx.x;
  int v = inp[b * SLEN + s];
  float4 x = ((const float4*)(emb + (size_t)v * EMB))[t];
  ushort4 o; o.x = f2bf(x.x); o.y = f2bf(x.y); o.z = f2bf(x.z); o.w = f2bf(x.w);
  ((ushort4*)(xbf + (size_t)row * EMB))[t] = o;
}

// ---------------- chunk GEMM (m97-style), unchanged from R2 ----------------
__global__ __launch_bounds__(256) void k_gemm(const ushort* __restrict__ A,
                                              const ushort* __restrict__ Bw,
                                              const float* __restrict__ bias,
                                              ushort* __restrict__ C, int K,
                                              size_t cDirStride){
  __shared__ __align__(16) ushort sA[128 * 32];
  __shared__ __align__(16) ushort sB[128 * 32];
  const int tid = threadIdx.x;
  const int d = blockIdx.z;
  const size_t mBase = (size_t)blockIdx.x * 128;
  const int nBase = blockIdx.y * 128;
  const ushort* Bd = Bw + (size_t)d * G4 * K;
  const float* biasd = bias + (size_t)d * G4;
  ushort* Cd = C + (size_t)d * cDirStride;
  const int w = tid >> 6, lane = tid & 63;
  const int quad = lane >> 4, c16 = lane & 15;
  const int m0 = (w >> 1) * 64, n0 = (w & 1) * 64;
  const int u0 = tid, u1 = tid + 256;
  const int r0 = u0 >> 2, k0 = (u0 & 3) * 8;
  const int r1 = u1 >> 2, k1 = (u1 & 3) * 8;

  f32x4 acc[4][4] = {};
  for (int kc = 0; kc < K; kc += 32){
    __syncthreads();
    async_ld16(A  + (mBase + r0) * (size_t)K + kc + k0, sA + u0 * 8);
    async_ld16(A  + (mBase + r1) * (size_t)K + kc + k1, sA + u1 * 8);
    async_ld16(Bd + (size_t)(nBase + r0) * K + kc + k0, sB + u0 * 8);
    async_ld16(Bd + (size_t)(nBase + r1) * K + kc + k1, sB + u1 * 8);
    __syncthreads();
    bf16x8 af[4], bfv[4];
#pragma unroll
    for (int mt = 0; mt < 4; ++mt)
      af[mt] = *(const bf16x8*)(sA + (m0 + mt * 16 + c16) * 32 + quad * 8);
#pragma unroll
    for (int nt = 0; nt < 4; ++nt)
      bfv[nt] = *(const bf16x8*)(sB + (n0 + nt * 16 + c16) * 32 + quad * 8);
#pragma unroll
    for (int mt = 0; mt < 4; ++mt)
#pragma unroll
      for (int nt = 0; nt < 4; ++nt)
        acc[mt][nt] = __builtin_amdgcn_mfma_f32_16x16x32_bf16(af[mt], bfv[nt], acc[mt][nt], 0, 0, 0);
  }
#pragma unroll
  for (int nt = 0; nt < 4; ++nt){
    int col = nBase + n0 + nt * 16 + c16;
    float bv = biasd[col];
#pragma unroll
    for (int mt = 0; mt < 4; ++mt){
      size_t rowb = mBase + m0 + mt * 16 + quad * 4;
#pragma unroll
      for (int r = 0; r < 4; ++r)
        Cd[(rowb + r) * G4 + col] = f2bf(acc[mt][nt][r] + bv);
    }
  }
}

// ---------------- relaxed grid barrier: monotonic count + generation ----------
// h-data visibility comes from write-through (sc0sc1) stores drained by the
// vmcnt(0) that __syncthreads emits; no cache wb/inv needed -> L2 stays warm.
__device__ __forceinline__ void grid_barrier256(unsigned* cnt, unsigned* gen, unsigned gbn){
  __atomic_signal_fence(__ATOMIC_SEQ_CST);
  __builtin_amdgcn_s_waitcnt(0);       // this wave's h stores are at LLC
  __syncthreads();                     // all waves drained (barrier also drains vmcnt)
  if (threadIdx.x == 0){
    unsigned old = __hip_atomic_fetch_add(cnt, 1u, __ATOMIC_RELAXED, __HIP_MEMORY_SCOPE_AGENT);
    if (old == (gbn + 1u) * 256u - 1u){
      __hip_atomic_fetch_add(gen, 1u, __ATOMIC_RELAXED, __HIP_MEMORY_SCOPE_AGENT);
    } else {
      while (__hip_atomic_load(gen, __ATOMIC_RELAXED, __HIP_MEMORY_SCOPE_AGENT) < gbn + 1u)
        __builtin_amdgcn_s_sleep(2);
    }
  }
  __syncthreads();
  __atomic_signal_fence(__ATOMIC_SEQ_CST);
}

// ---------------- persistent recurrent kernel for ONE chunk of CT steps ----------
// 256 blocks = (dir, 16-hidden-unit tile, batch-half of 32). 4 waves = 4 gates.
// Each wave holds its gate's full K=1024 B-fragments in 128 VGPRs (loaded once).
// h slots: rolling CT-slot buffer, each address written exactly once per dispatch
// via write-through relaxed agent atomic stores (packed 2xbf16 -> u32).
__global__ __launch_bounds__(256, 1) void k_rec(const ushort* __restrict__ xw,
                                                const ushort* __restrict__ whh,
                                                const ushort* __restrict__ hinit,
                                                ushort* __restrict__ hseq,
                                                float* __restrict__ cst,
                                                unsigned* __restrict__ bar,
                                                int mode, int tbase, unsigned barBase,
                                                const int* __restrict__ tgt_idx,
                                                float* __restrict__ tgt_out){
  const int tid = threadIdx.x;
  const int bx = blockIdx.x;
  const int d  = bx >> 7;                 // direction
  const int jt = (bx & 127) >> 1;         // hidden tile (16 units)
  const int mh = bx & 1;                  // batch half
  const int j0 = jt * 16;
  const int mb = mh * 32;
  const int w = tid >> 6, lane = tid & 63;
  const int quad = lane >> 4, c16 = lane & 15;
  const int g = w;                        // wave's gate (torch order i,f,g,o)
  const int er = tid >> 3;                // epilogue: batch row 0..31
  const int ec = (tid & 7) * 2;           // epilogue: col pair 0,2,..,14

  __shared__ float sred[4 * 32 * 17];     // [gate][row32][col16+pad]

  unsigned* cnt = bar;
  unsigned* gen = bar + 32;

  // ---- preload this wave's gate weights: 32 frags x 16B = 128 VGPRs ----
  bf16x8 bfr[32];
  {
    const ushort* wp = whh + ((size_t)d * G4 + g * HID + j0 + c16) * HID + quad * 8;
#pragma unroll
    for (int t = 0; t < 32; ++t) bfr[t] = *(const bf16x8*)(wp + t * 32);
  }

  // ---- cell state: 2 units per thread, registers across the chunk ----
  float cv0 = cst[(size_t)bx * 512 + tid * 2];
  float cv1 = cst[(size_t)bx * 512 + tid * 2 + 1];

  const int tgt_t = mode ? tgt_idx[mb + er] : -1;

  for (int i = 0; i < CT; ++i){
    const ushort* hprev = (i == 0) ? hinit : hseq + (size_t)(i - 1) * HSLOT;
    ushort* hout = hseq + (size_t)i * HSLOT;

    // xw pre-activations for this thread's 2 units x 4 gates (independent: issue early)
    const size_t xrow = ((size_t)d * CROWS + (size_t)i * NBATCH + mb + er) * G4;
    uint32_t xq0 = *(const uint32_t*)(xw + xrow + 0 * HID + j0 + ec);
    uint32_t xq1 = *(const uint32_t*)(xw + xrow + 1 * HID + j0 + ec);
    uint32_t xq2 = *(const uint32_t*)(xw + xrow + 2 * HID + j0 + ec);
    uint32_t xq3 = *(const uint32_t*)(xw + xrow + 3 * HID + j0 + ec);

    // ---- K-loop: h(t-1) x W_hh for this gate, 2 batch tiles of 16 ----
    f32x4 acc0 = {}, acc1 = {};
    const ushort* ap = hprev + (size_t)(mb + c16) * D2H + d * HID + quad * 8;
#pragma unroll
    for (int t = 0; t < 32; ++t){
      bf16x8 a0 = *(const bf16x8*)(ap + t * 32);
      bf16x8 a1 = *(const bf16x8*)(ap + (size_t)16 * D2H + t * 32);
      acc0 = __builtin_amdgcn_mfma_f32_16x16x32_bf16(a0, bfr[t], acc0, 0, 0, 0);
      acc1 = __builtin_amdgcn_mfma_f32_16x16x32_bf16(a1, bfr[t], acc1, 0, 0, 0);
    }

    // ---- stash gate tiles to LDS (D layout: col=c16, row=quad*4+r) ----
#pragma unroll
    for (int r = 0; r < 4; ++r){
      sred[(g * 32 + quad * 4 + r) * 17 + c16]      = acc0[r];
      sred[(g * 32 + 16 + quad * 4 + r) * 17 + c16] = acc1[r];
    }
    __syncthreads();

    // ---- per-thread LSTM pointwise for units (er,ec) and (er,ec+1) ----
    float i0 = sred[(0 * 32 + er) * 17 + ec]     + bf2f(xq0 & 0xffffu);
    float i1 = sred[(0 * 32 + er) * 17 + ec + 1] + bf2f(xq0 >> 16);
    float f0 = sred[(1 * 32 + er) * 17 + ec]     + bf2f(xq1 & 0xffffu);
    float f1 = sred[(1 * 32 + er) * 17 + ec + 1] + bf2f(xq1 >> 16);
    float g0 = sred[(2 * 32 + er) * 17 + ec]     + bf2f(xq2 & 0xffffu);
    float g1 = sred[(2 * 32 + er) * 17 + ec + 1] + bf2f(xq2 >> 16);
    float o0 = sred[(3 * 32 + er) * 17 + ec]     + bf2f(xq3 & 0xffffu);
    float o1 = sred[(3 * 32 + er) * 17 + ec + 1] + bf2f(xq3 >> 16);
    float c0 = sigm(f0) * cv0 + sigm(i0) * tanh_s(g0);
    float c1 = sigm(f1) * cv1 + sigm(i1) * tanh_s(g1);
    float h0 = sigm(o0) * tanh_s(c0);
    float h1 = sigm(o1) * tanh_s(c1);
    cv0 = c0; cv1 = c1;

    // write-through packed h (reaches LLC; drained by barrier)
    uint32_t hp = (uint32_t)f2bf(h0) | ((uint32_t)f2bf(h1) << 16);
    size_t hoff = (size_t)(mb + er) * D2H + d * HID + j0 + ec;
    __hip_atomic_store((uint32_t*)(hout + hoff), hp, __ATOMIC_RELAXED, __HIP_MEMORY_SCOPE_AGENT);

    if (mode && tgt_t == tbase + i){
      tgt_out[hoff]     = h0;
      tgt_out[hoff + 1] = h1;
    }

    if (i != CT - 1) grid_barrier256(cnt, gen, barBase + (unsigned)i);
  }

  cst[(size_t)bx * 512 + tid * 2]     = cv0;
  cst[(size_t)bx * 512 + tid * 2 + 1] = cv1;
}

// ---------------- final: out[b] = sigmoid(dot(tgt[b], w_cls) + b_cls) ----------------
__global__ __launch_bounds__(256) void k_final(const float* __restrict__ tgt,
                                               const float* __restrict__ wc,
                                               const float* __restrict__ bc,
                                               float* __restrict__ out){
  int b = blockIdx.x, tid = threadIdx.x;
  const float4* tv = (const float4*)(tgt + (size_t)b * D2H);
  const float4* wv = (const float4*)wc;
  float s = 0.f;
  for (int i = tid; i < D2H / 4; i += 256){
    float4 a = tv[i], ww = wv[i];
    s += a.x * ww.x + a.y * ww.y + a.z * ww.z + a.w * ww.w;
  }
  for (int off = 32; off; off >>= 1) s += __shfl_down(s, off, 64);
  __shared__ float red[4];
  if ((tid & 63) == 0) red[tid >> 6] = s;
  __syncthreads();
  if (tid == 0){
    float tot = red[0] + red[1] + red[2] + red[3] + bc[0];
    out[b] = 1.f / (1.f + __expf(-tot));
  }
}

extern "C" void kernel_launch(void* const* d_in, const int* in_sizes, int n_in,
                              void* d_out, int out_size, void* d_ws, size_t ws_size,
                              hipStream_t stream){
  (void)in_sizes; (void)n_in; (void)out_size; (void)ws_size;
  const int*   inp   = (const int*)  d_in[0];
  const int*   tgtix = (const int*)  d_in[1];
  const float* emb   = (const float*)d_in[2];
  const float* wih0  = (const float*)d_in[3];
  const float* whh0  = (const float*)d_in[4];
  const float* bl0   = (const float*)d_in[5];
  const float* wih1  = (const float*)d_in[6];
  const float* whh1  = (const float*)d_in[7];
  const float* bl1   = (const float*)d_in[8];
  const float* wcls  = (const float*)d_in[9];
  const float* bcls  = (const float*)d_in[10];
  float* out = (float*)d_out;

  // ---- workspace carve (~187 MB total) ----
  char* p = (char*)d_ws;
  ushort* wih0b = (ushort*)p; p += (size_t)2 * G4 * 1024 * 2;   // 16 MB
  ushort* whh0b = (ushort*)p; p += (size_t)2 * G4 * 1024 * 2;   // 16 MB
  ushort* wih1b = (ushort*)p; p += (size_t)2 * G4 * 2048 * 2;   // 32 MB
  ushort* whh1b = (ushort*)p; p += (size_t)2 * G4 * 1024 * 2;   // 16 MB
  ushort* xbf   = (ushort*)p; p += (size_t)CROWS * EMB * 2;     // 8 MB
  ushort* xw    = (ushort*)p; p += (size_t)2 * CROWS * G4 * 2;  // 64 MB
  ushort* h0seq = (ushort*)p; p += (size_t)CT * HSLOT * 2;      // 16 MB rolling
  ushort* h1seq = (ushort*)p; p += (size_t)CT * HSLOT * 2;      // 16 MB rolling
  // ---- zeroed region ----
  char* zbase = p;
  ushort* h0zero = (ushort*)p; p += (size_t)HSLOT * 2;            // 256 KB
  float*  c0st   = (float*)p;  p += (size_t)256 * 512 * 4;        // 512 KB
  float*  c1st   = (float*)p;  p += (size_t)256 * 512 * 4;        // 512 KB
  unsigned* bar  = (unsigned*)p; p += 1024;
  size_t zbytes = (size_t)(p - zbase);
  // ---- end zero region ----
  float* tgtb = (float*)p; p += (size_t)NBATCH * D2H * 4;       // 512 KB

  int zn = (int)(zbytes / 4);
  k_zero<<<dim3((zn + 255) / 256), 256, 0, stream>>>((uint32_t*)zbase, zn);
  k_convert<<<dim3(8192),  256, 0, stream>>>((const float4*)wih0, (ushort4*)wih0b, 2 * G4 * 1024 / 4);
  k_convert<<<dim3(8192),  256, 0, stream>>>((const float4*)whh0, (ushort4*)whh0b, 2 * G4 * 1024 / 4);
  k_convert<<<dim3(16384), 256, 0, stream>>>((const float4*)wih1, (ushort4*)wih1b, 2 * G4 * 2048 / 4);
  k_convert<<<dim3(8192),  256, 0, stream>>>((const float4*)whh1, (ushort4*)whh1b, 2 * G4 * 1024 / 4);

  const size_t cds = (size_t)CROWS * G4;
  for (int c = 0; c < NC; ++c){
    int tbase = c * CT;
    k_gather_c<<<dim3(CROWS), 256, 0, stream>>>(inp, emb, xbf, tbase);
    // layer 0
    k_gemm<<<dim3(CROWS / 128, G4 / 128, 2), 256, 0, stream>>>(xbf, wih0b, bl0, xw, EMB, cds);
    k_rec<<<dim3(256), 256, 0, stream>>>(xw, whh0b,
                                         c == 0 ? h0zero : h0seq + (size_t)(CT - 1) * HSLOT,
                                         h0seq, c0st, bar, 0, tbase,
                                         (unsigned)(2 * c) * 63u, tgtix, tgtb);
    // layer 1
    k_gemm<<<dim3(CROWS / 128, G4 / 128, 2), 256, 0, stream>>>(h0seq, wih1b, bl1, xw, D2H, cds);
    k_rec<<<dim3(256), 256, 0, stream>>>(xw, whh1b,
                                         c == 0 ? h0zero : h1seq + (size_t)(CT - 1) * HSLOT,
                                         h1seq, c1st, bar, 1, tbase,
                                         (unsigned)(2 * c + 1) * 63u, tgtix, tgtb);
  }

  k_final<<<dim3(NBATCH), 256, 0, stream>>>(tgtb, wcls, bcls, out);
}